// Round 14
// baseline (393.927 us; speedup 1.0000x reference)
//
#include <hip/hip_runtime.h>
#include <hip/hip_fp16.h>
#include <cstdint>

#define DH 64
#define EPSV 1e-5f
#define GBLK 2048
#define NBUK 256
#define BROWS 512
#define BINJ 8
#define CAP 12288

typedef _Float16 half8 __attribute__((ext_vector_type(8)));
typedef float f32x4 __attribute__((ext_vector_type(4)));

// init bucket stage cursors: gcur0[b] = b*CAP
__global__ void k_gcur0(unsigned* __restrict__ gcur0) {
  gcur0[threadIdx.x] = (unsigned)(threadIdx.x * CAP);
}

// x (fp32 [N][100]) -> xh (fp16 [N][128], zero-padded). float4-coalesced.
__global__ __launch_bounds__(256) void k_xhalf(const float* __restrict__ x,
                                               unsigned short* __restrict__ xh,
                                               int N_, int K) {
  const int cpr = K / 4;
  size_t i = blockIdx.x * 256ull + threadIdx.x;
  if (i >= (size_t)N_ * cpr) return;
  int row = (int)(i / cpr), c0 = (int)(i % cpr) * 4;
  float4 v = *(const float4*)&x[(size_t)row * K + c0];
  ushort4 h;
  h.x = __half_as_ushort(__float2half(v.x));
  h.y = __half_as_ushort(__float2half(v.y));
  h.z = __half_as_ushort(__float2half(v.z));
  h.w = __half_as_ushort(__float2half(v.w));
  *(ushort4*)&xh[(size_t)row * 128 + c0] = h;
  if (c0 == K - 4) {
    ushort4 z4 = {0, 0, 0, 0};
    uint4 z16 = {0, 0, 0, 0};
    *(ushort4*)&xh[(size_t)row * 128 + K] = z4;
    *(uint4*)&xh[(size_t)row * 128 + K + 4] = z16;
    *(uint4*)&xh[(size_t)row * 128 + K + 12] = z16;
    *(uint4*)&xh[(size_t)row * 128 + K + 20] = z16;
  }
}

// W (fp32 [Kreal][64]) -> wt (fp16 [64][KP], zero-padded transpose)
__global__ void k_wt(const float* __restrict__ W, unsigned short* __restrict__ wt,
                     int Kreal, int KP) {
  int idx = blockIdx.x * 256 + threadIdx.x;
  if (idx >= 64 * KP) return;
  int c = idx / KP, k = idx % KP;
  float v = (k < Kreal) ? W[k * DH + c] : 0.f;
  wt[idx] = __half_as_ushort(__float2half(v));
}

// Pass 1: bin edges by dst bucket. payload: hi=(dst&511)<<17|src, lo=fp32 ew.
__global__ __launch_bounds__(256) void k_bin0(
    const int* __restrict__ src, const int* __restrict__ dst,
    const float* __restrict__ ew, unsigned* __restrict__ gcur0,
    unsigned long long* __restrict__ bstage, int E_) {
  __shared__ unsigned cntL[NBUK], offL[NBUK], runL[NBUK];
  const int t = threadIdx.x;
  const int base = blockIdx.x * (256 * BINJ);
  cntL[t] = 0;
  runL[t] = 0;
  __syncthreads();
  unsigned hi[BINJ], lo[BINJ];
  int bb[BINJ];
#pragma unroll
  for (int j = 0; j < BINJ; ++j) {
    int e = base + j * 256 + t;
    bb[j] = -1;
    if (e < E_) {
      int q = dst[e];
      hi[j] = ((unsigned)(q & (BROWS - 1)) << 17) | (unsigned)src[e];
      lo[j] = __float_as_uint(ew[e]);
      bb[j] = q >> 9;
      atomicAdd(&cntL[bb[j]], 1u);
    }
  }
  __syncthreads();
  offL[t] = cntL[t] ? atomicAdd(&gcur0[t], cntL[t]) : 0u;
  __syncthreads();
#pragma unroll
  for (int j = 0; j < BINJ; ++j) {
    if (bb[j] >= 0) {
      unsigned p = offL[bb[j]] + atomicAdd(&runL[bb[j]], 1u);
      bstage[p] = ((unsigned long long)hi[j] << 32) | lo[j];
    }
  }
}

// Per-bucket histogram from staged runs (deterministic fixed-point sum).
__global__ __launch_bounds__(256) void k_bcnt(
    const unsigned long long* __restrict__ bstage, const unsigned* __restrict__ gcur0,
    int* __restrict__ cnt, float* __restrict__ dinv, float* __restrict__ sc, int N_) {
  __shared__ unsigned cntL[BROWS], degL[BROWS];
  const int b = blockIdx.x, t = threadIdx.x;
  for (int i = t; i < BROWS; i += 256) {
    cntL[i] = 0;
    degL[i] = 0;
  }
  __syncthreads();
  const unsigned beg = (unsigned)(b * CAP), end = gcur0[b];
  for (unsigned p = beg + t; p < end; p += 256) {
    unsigned long long v = bstage[p];
    unsigned r = (unsigned)(v >> 49);
    float w = __uint_as_float((unsigned)v);
    atomicAdd(&cntL[r], 1u);
    atomicAdd(&degL[r], (unsigned)(w * 16777216.0f));
  }
  __syncthreads();
  for (int i = t; i < BROWS; i += 256) {
    int r = b * BROWS + i;
    if (r < N_) {
      float deg = 1.0f + (float)degL[i] * (1.0f / 16777216.0f);
      cnt[r] = (int)cntL[i];
      dinv[r] = rsqrtf(deg);
      sc[r] = 1.0f / deg;
    }
  }
}

// ---- exclusive scan over n1 = N+1 values (raw cnt, no padding) ----
__global__ __launch_bounds__(256) void k_scan1(const int* __restrict__ cnt,
                                               int* __restrict__ out,
                                               int* __restrict__ bsums,
                                               int N_, int n1) {
  __shared__ int sm[256];
  const int t = threadIdx.x;
  const int base = blockIdx.x * 1024 + t * 4;
  int v[4], lsum = 0;
#pragma unroll
  for (int j = 0; j < 4; ++j) {
    int i = base + j;
    v[j] = (i < N_) ? cnt[i] : 0;
    lsum += v[j];
  }
  sm[t] = lsum;
  __syncthreads();
  for (int o = 1; o < 256; o <<= 1) {
    int x = (t >= o) ? sm[t - o] : 0;
    __syncthreads();
    if (t >= o) sm[t] += x;
    __syncthreads();
  }
  int run = sm[t] - lsum;
#pragma unroll
  for (int j = 0; j < 4; ++j) {
    int i = base + j;
    if (i < n1) out[i] = run;
    run += v[j];
  }
  if (t == 255) bsums[blockIdx.x] = sm[255];
}

__global__ __launch_bounds__(256) void k_scan2(int* __restrict__ bsums, int nb) {
  __shared__ int sm[256];
  int t = threadIdx.x;
  int v = (t < nb) ? bsums[t] : 0;
  sm[t] = v;
  __syncthreads();
  for (int o = 1; o < 256; o <<= 1) {
    int x = (t >= o) ? sm[t - o] : 0;
    __syncthreads();
    if (t >= o) sm[t] += x;
    __syncthreads();
  }
  if (t < nb) bsums[t] = sm[t] - v;
}

__global__ void k_scan3(int* __restrict__ out, const int* __restrict__ bsums, int n1) {
  int i = blockIdx.x * blockDim.x + threadIdx.x;
  if (i < n1) out[i] += bsums[i >> 10];
}

// Pass 2: one block per bucket; norm + CSR placement via LDS cursors.
__global__ __launch_bounds__(256) void k_fin(
    const unsigned long long* __restrict__ bstage, const int* __restrict__ rowstart,
    const unsigned* __restrict__ gcur0, const float* __restrict__ dinv,
    unsigned* __restrict__ elist, int N_) {
  __shared__ unsigned lcur[BROWS];
  __shared__ int rsL[BROWS];
  __shared__ float dvL[BROWS];
  const int b = blockIdx.x, t = threadIdx.x;
  const int r0 = b * BROWS;
  for (int i = t; i < BROWS; i += 256) {
    lcur[i] = 0;
    int r = r0 + i;
    dvL[i] = (r < N_) ? dinv[r] : 0.f;
    rsL[i] = (r < N_) ? rowstart[r] : 0;
  }
  __syncthreads();
  const unsigned beg = (unsigned)(b * CAP), end = gcur0[b];
  for (unsigned p = beg + t; p < end; p += 256) {
    unsigned long long v = bstage[p];
    unsigned hi = (unsigned)(v >> 32);
    unsigned r = hi >> 17;
    unsigned s = hi & 0x1FFFFu;
    float w = __uint_as_float((unsigned)v);
    float nm = w * dinv[s] * dvL[r];
    unsigned h15 = (unsigned)__half_as_ushort(__float2half(nm));
    unsigned slot = (unsigned)rsL[r] + atomicAdd(&lcur[r], 1u);
    elist[slot] = (h15 << 17) | s;
  }
}

// graph boundary detection on sorted batch: gstart[g] for g in [0,G]
__global__ void k_gbound(const int* __restrict__ batch, int* __restrict__ gstart,
                         int N_, int G_) {
  int i = blockIdx.x * blockDim.x + threadIdx.x;
  if (i >= N_) return;
  int b = batch[i];
  if (i == 0) {
    for (int g = 0; g <= b; ++g) gstart[g] = 0;
  }
  int nb = (i + 1 < N_) ? batch[i + 1] : G_;
  for (int g = b + 1; g <= nb; ++g) gstart[g] = i + 1;
}

// MFMA GEMM: 128x64/block. A from xh [N][128] (layer0) or plane pair
// AGG0/AGG1 [N][32] (FUSE). H written as planes H0/H1 [N][32] fp16.
template <int KP, int FUSE>
__global__ __launch_bounds__(256) void k_gemm_mfma(
    const unsigned short* __restrict__ A0, const unsigned short* __restrict__ A1,
    const unsigned short* __restrict__ wt, const float* __restrict__ bias,
    const float* __restrict__ stats, const float* __restrict__ gam,
    const float* __restrict__ bet, unsigned short* __restrict__ Hu0,
    unsigned short* __restrict__ Hu1, int n, float invN) {
  __shared__ unsigned short Ah[128 * KP];
  __shared__ unsigned short Bt[64 * KP];
  __shared__ float saL[DH], sbL[DH];
  const int tid = threadIdx.x;
  const int r0 = blockIdx.x * 128;
  if (FUSE) {
    if (tid < DH) {
      float mean = stats[tid] * invN;
      float var = stats[DH + tid] * invN - mean * mean;
      float a = rsqrtf(var + EPSV) * gam[tid];
      saL[tid] = a;
      sbL[tid] = bet[tid] - mean * a;
    }
    __syncthreads();
  }
  constexpr int KC = KP / 8;
  for (int ci = tid; ci < 128 * KC; ci += 256) {
    int row = ci / KC, kc = ci % KC, k0 = kc * 8;
    int gr = r0 + row;
    uint4 av = {0, 0, 0, 0};
    if (gr < n) {
      if (FUSE) {
        const unsigned short* P = (kc < KC / 2) ? A0 : A1;
        av = *(const uint4*)&P[(size_t)gr * 32 + (k0 & 31)];
      } else {
        av = *(const uint4*)&A0[(size_t)gr * KP + k0];
      }
    }
    if (FUSE) {
      const unsigned short* ap = (const unsigned short*)&av;
      unsigned short ov[8];
#pragma unroll
      for (int j = 0; j < 8; ++j) {
        int k = k0 + j;
        float a = __half2float(__ushort_as_half(ap[j]));
        ov[j] = __half_as_ushort(__float2half(fmaxf(a * saL[k] + sbL[k], 0.f)));
      }
      av = *(uint4*)ov;
    }
    *(uint4*)&Ah[row * KP + (k0 ^ ((row & 7) * 8))] = av;
  }
  for (int ci = tid; ci < 64 * KC; ci += 256) {
    int c = ci / KC, kc = ci % KC, k0 = kc * 8;
    uint4 wv = *(const uint4*)&wt[c * KP + k0];
    *(uint4*)&Bt[c * KP + (k0 ^ ((c & 7) * 8))] = wv;
  }
  __syncthreads();
  const int w = tid >> 6, l = tid & 63;
  const int lr = l & 15, lg = l >> 4;
  f32x4 acc[2][4];
#pragma unroll
  for (int a1 = 0; a1 < 2; ++a1)
#pragma unroll
    for (int a2 = 0; a2 < 4; ++a2) acc[a1][a2] = (f32x4){0.f, 0.f, 0.f, 0.f};
#pragma unroll
  for (int ks = 0; ks < KP / 32; ++ks) {
    const int k0 = ks * 32 + lg * 8;
    half8 av[2], bv[4];
#pragma unroll
    for (int rf = 0; rf < 2; ++rf) {
      int row = w * 32 + rf * 16 + lr;
      av[rf] = *(const half8*)&Ah[row * KP + (k0 ^ ((row & 7) * 8))];
    }
#pragma unroll
    for (int cf = 0; cf < 4; ++cf) {
      int col = cf * 16 + lr;
      bv[cf] = *(const half8*)&Bt[col * KP + (k0 ^ ((col & 7) * 8))];
    }
#pragma unroll
    for (int rf = 0; rf < 2; ++rf)
#pragma unroll
      for (int cf = 0; cf < 4; ++cf)
        acc[rf][cf] =
            __builtin_amdgcn_mfma_f32_16x16x32_f16(av[rf], bv[cf], acc[rf][cf], 0, 0, 0);
  }
#pragma unroll
  for (int rf = 0; rf < 2; ++rf) {
#pragma unroll
    for (int cf = 0; cf < 4; ++cf) {
      int col = cf * 16 + lr;
      float bcol = bias[col];
      unsigned short* Hp = (col < 32) ? Hu0 : Hu1;
#pragma unroll
      for (int i = 0; i < 4; ++i) {
        int row = r0 + w * 32 + rf * 16 + lg * 4 + i;
        if (row < n)
          Hp[(size_t)row * 32 + (col & 31)] =
              __half_as_ushort(__float2half(acc[rf][cf][i] + bcol));
      }
    }
  }
}

// Plane gather: wave per dst row; lanes 0-31 = features of the plane,
// half-waves process edge pairs; pad-free (register roundup, eL=0 no-ops).
__global__ __launch_bounds__(256) void k_gather2(
    const unsigned* __restrict__ elist, const int* __restrict__ rowstart,
    const unsigned short* __restrict__ Hp, const float* __restrict__ sc,
    unsigned short* __restrict__ AGGp, float* __restrict__ statp, int n, int pofs) {
  const int wid = threadIdx.x >> 6;
  const int lane = threadIdx.x & 63;
  const int d = lane & 31;
  const int h = lane >> 5;
  const int gw = blockIdx.x * 4 + wid;
  const int nw = gridDim.x * 4;
  float s = 0.f, ss = 0.f;
  for (int row = gw; row < n; row += nw) {
    const int rs = rowstart[row], re = rowstart[row + 1];
    float acc = (h == 0)
        ? __half2float(__ushort_as_half(Hp[(size_t)row * 32 + d])) * sc[row]
        : 0.f;
    for (int base = rs; base < re; base += 64) {
      const int rem = re - base;
      unsigned eL = 0u;
      if (lane < rem) eL = __builtin_nontemporal_load(&elist[base + lane]);
      const int m = rem < 64 ? ((rem + 7) & ~7) : 64;
      for (int j = 0; j < m; j += 8) {
        unsigned e[4];
        float v[4];
#pragma unroll
        for (int jj = 0; jj < 4; ++jj) e[jj] = __shfl(eL, j + jj * 2 + h, 64);
#pragma unroll
        for (int jj = 0; jj < 4; ++jj)
          v[jj] = __half2float(__ushort_as_half(Hp[(size_t)(e[jj] & 0x1FFFFu) * 32 + d]));
#pragma unroll
        for (int jj = 0; jj < 4; ++jj) {
          float nm = __half2float(__ushort_as_half((unsigned short)(e[jj] >> 17)));
          acc = fmaf(nm, v[jj], acc);
        }
      }
    }
    float other = __shfl_down(acc, 32, 64);
    if (h == 0) {
      float full = acc + other;
      __builtin_nontemporal_store(__half_as_ushort(__float2half(full)),
                                  &AGGp[(size_t)row * 32 + d]);
      s += full;
      ss += full * full;
    }
  }
  __shared__ float sm[4][32], sm2[4][32];
  if (h == 0) {
    sm[wid][d] = s;
    sm2[wid][d] = ss;
  }
  __syncthreads();
  if (threadIdx.x < 32) {
    float a = sm[0][d] + sm[1][d] + sm[2][d] + sm[3][d];
    float b = sm2[0][d] + sm2[1][d] + sm2[2][d] + sm2[3][d];
    __builtin_nontemporal_store(a, &statp[(size_t)blockIdx.x * 128 + pofs + d]);
    __builtin_nontemporal_store(b, &statp[(size_t)blockIdx.x * 128 + 64 + pofs + d]);
  }
}

// reduce per-block stat partials: one block per stat entry (128 blocks)
__global__ __launch_bounds__(256) void k_redstats(const float* __restrict__ statp,
                                                  float* __restrict__ stats, int nblk) {
  const int t = blockIdx.x;
  float s = 0.f;
  for (int b = threadIdx.x; b < nblk; b += 256) s += statp[(size_t)b * 128 + t];
#pragma unroll
  for (int o = 32; o > 0; o >>= 1) s += __shfl_down(s, o, 64);
  __shared__ float sm[4];
  if ((threadIdx.x & 63) == 0) sm[threadIdx.x >> 6] = s;
  __syncthreads();
  if (threadIdx.x == 0) stats[t] = sm[0] + sm[1] + sm[2] + sm[3];
}

// fused BN+ReLU+mean-pool+head: one block per graph (plane reads).
__global__ __launch_bounds__(256) void k_poolhead(
    const unsigned short* __restrict__ A0, const unsigned short* __restrict__ A1,
    const float* __restrict__ stats, const float* __restrict__ gam,
    const float* __restrict__ bet, const float* __restrict__ ow,
    const int* __restrict__ gstart, const float* __restrict__ ob,
    float* __restrict__ out, float invN) {
  const int g = blockIdx.x;
  const int gs = gstart[g], ge = gstart[g + 1];
  const int wid = threadIdx.x >> 6;
  const int d = threadIdx.x & 63;
  float mean = stats[d] * invN;
  float var = stats[DH + d] * invN - mean * mean;
  float sa = rsqrtf(var + EPSV) * gam[d];
  float sb = bet[d] - mean * sa;
  const float w = ow[d];
  const unsigned short* P = (d < 32) ? A0 : A1;
  const int dl = d & 31;
  float acc = 0.f;
  for (int row = gs + wid; row < ge; row += 4) {
    float v = __half2float(__ushort_as_half(P[(size_t)row * 32 + dl]));
    acc += fmaxf(v * sa + sb, 0.f) * w;
  }
#pragma unroll
  for (int off = 32; off > 0; off >>= 1) acc += __shfl_down(acc, off, 64);
  __shared__ float sm[4];
  if (d == 0) sm[wid] = acc;
  __syncthreads();
  if (threadIdx.x == 0) {
    float s = sm[0] + sm[1] + sm[2] + sm[3];
    float cnt = (float)(ge - gs);
    out[g] = s / fmaxf(cnt, 1.0f) + ob[0];
  }
}

extern "C" void kernel_launch(void* const* d_in, const int* in_sizes, int n_in,
                              void* d_out, int out_size, void* d_ws, size_t ws_size,
                              hipStream_t stream) {
  const float* x    = (const float*)d_in[0];
  const int*   ei   = (const int*)d_in[1];
  const float* ew   = (const float*)d_in[2];
  const int*   batch= (const int*)d_in[3];
  const float* w0   = (const float*)d_in[4];
  const float* b0   = (const float*)d_in[5];
  const float* g0   = (const float*)d_in[6];
  const float* be0  = (const float*)d_in[7];
  const float* w1   = (const float*)d_in[8];
  const float* b1   = (const float*)d_in[9];
  const float* g1   = (const float*)d_in[10];
  const float* be1  = (const float*)d_in[11];
  const float* w2   = (const float*)d_in[12];
  const float* b2   = (const float*)d_in[13];
  const float* g2   = (const float*)d_in[14];
  const float* be2  = (const float*)d_in[15];
  const float* ow   = (const float*)d_in[16];
  const float* ob   = (const float*)d_in[17];

  const int N_  = in_sizes[3];
  const int E_  = in_sizes[2];
  const int DIN_= in_sizes[0] / N_;
  const int G_  = out_size;
  const int* srcIdx = ei;
  const int* dstIdx = ei + E_;
  const int n1 = N_ + 1;

  float* ws = (float*)d_ws;
  size_t off = 0;
  unsigned long long* bstage = (unsigned long long*)(ws + off);
  off += (size_t)2 * NBUK * CAP;
  unsigned* elist = (unsigned*)(ws + off); off += E_;
  float* dinv     = ws + off; off += N_;
  float* sc       = ws + off; off += N_;
  int*   cnt      = (int*)(ws + off); off += N_;
  int*   rowstart = (int*)(ws + off); off += n1 + 1;
  int*   bsums    = (int*)(ws + off); off += 256;
  unsigned* gcur0 = (unsigned*)(ws + off); off += NBUK;
  int*   gstart   = (int*)(ws + off); off += G_ + 1;
  unsigned short* h0   = (unsigned short*)(ws + off); off += (size_t)N_ * 16;
  unsigned short* h1   = (unsigned short*)(ws + off); off += (size_t)N_ * 16;
  unsigned short* agg0 = (unsigned short*)(ws + off); off += (size_t)N_ * 16;
  unsigned short* agg1 = (unsigned short*)(ws + off); off += (size_t)N_ * 16;
  unsigned short* xh = (unsigned short*)(ws + off); off += (size_t)N_ * 64;
  unsigned short* wt0 = (unsigned short*)(ws + off); off += 64 * 128 / 2;
  unsigned short* wt1 = (unsigned short*)(ws + off); off += 64 * 64 / 2;
  unsigned short* wt2 = (unsigned short*)(ws + off); off += 64 * 64 / 2;
  float* stats    = ws + off; off += 2 * DH;
  float* statp    = ws + off; off += (size_t)GBLK * 128;
  (void)ws_size; (void)n_in;

  // --- operand pre-conversion ---
  k_xhalf<<<(int)(((size_t)N_ * (DIN_ / 4) + 255) / 256), 256, 0, stream>>>(x, xh, N_, DIN_);
  k_wt<<<(64 * 128 + 255) / 256, 256, 0, stream>>>(w0, wt0, DIN_, 128);
  k_wt<<<(64 * 64 + 255) / 256, 256, 0, stream>>>(w1, wt1, DH, 64);
  k_wt<<<(64 * 64 + 255) / 256, 256, 0, stream>>>(w2, wt2, DH, 64);

  // --- binned CSR build (pad-free) ---
  k_gcur0<<<1, NBUK, 0, stream>>>(gcur0);
  k_bin0<<<(E_ + 256 * BINJ - 1) / (256 * BINJ), 256, 0, stream>>>(
      srcIdx, dstIdx, ew, gcur0, bstage, E_);
  k_bcnt<<<NBUK, 256, 0, stream>>>(bstage, gcur0, cnt, dinv, sc, N_);

  const int nb = (n1 + 1023) / 1024;
  k_scan1<<<nb, 256, 0, stream>>>(cnt, rowstart, bsums, N_, n1);
  k_scan2<<<1, 256, 0, stream>>>(bsums, nb);
  k_scan3<<<(n1 + 255) / 256, 256, 0, stream>>>(rowstart, bsums, n1);

  k_fin<<<NBUK, 256, 0, stream>>>(bstage, rowstart, gcur0, dinv, elist, N_);

  // --- graph boundaries for pooling ---
  k_gbound<<<(N_ + 255) / 256, 256, 0, stream>>>(batch, gstart, N_, G_);

  const float* Bl[3]  = {b0, b1, b2};
  const float* Gl[3]  = {g0, g1, g2};
  const float* BeL[3] = {be0, be1, be2};
  const unsigned short* Wt[3] = {wt0, wt1, wt2};

  const float invN = 1.0f / (float)N_;
  const int gblk = (N_ + 127) / 128;

  for (int l = 0; l < 3; ++l) {
    if (l == 0) {
      k_gemm_mfma<128, 0><<<gblk, 256, 0, stream>>>(
          xh, nullptr, Wt[0], Bl[0], stats, nullptr, nullptr, h0, h1, N_, invN);
    } else {
      k_gemm_mfma<64, 1><<<gblk, 256, 0, stream>>>(
          agg0, agg1, Wt[l], Bl[l], stats, Gl[l - 1], BeL[l - 1], h0, h1, N_, invN);
    }
    k_gather2<<<GBLK, 256, 0, stream>>>(elist, rowstart, h0, sc, agg0, statp, N_, 0);
    k_gather2<<<GBLK, 256, 0, stream>>>(elist, rowstart, h1, sc, agg1, statp, N_, 32);
    k_redstats<<<128, 256, 0, stream>>>(statp, stats, GBLK);
  }

  // --- fused BN2+ReLU+pooling+head ---
  k_poolhead<<<G_, 256, 0, stream>>>(agg0, agg1, stats, g2, be2, ow, gstart, ob,
                                     (float*)d_out, invN);
}

// Round 15
// 336.813 us; speedup vs baseline: 1.1696x; 1.1696x over previous
//
#include <hip/hip_runtime.h>
#include <hip/hip_fp16.h>
#include <cstdint>

#define DH 64
#define EPSV 1e-5f
#define GBLK 2048
#define NBUK 256
#define BROWS 512
#define BINJ 8
#define CAP 12288

typedef _Float16 half8 __attribute__((ext_vector_type(8)));
typedef float f32x4 __attribute__((ext_vector_type(4)));

// init bucket stage cursors: gcur0[b] = b*CAP
__global__ void k_gcur0(unsigned* __restrict__ gcur0) {
  gcur0[threadIdx.x] = (unsigned)(threadIdx.x * CAP);
}

// x (fp32 [N][100]) -> xh (fp16 [N][128], zero-padded). float4-coalesced.
__global__ __launch_bounds__(256) void k_xhalf(const float* __restrict__ x,
                                               unsigned short* __restrict__ xh,
                                               int N_, int K) {
  const int cpr = K / 4;
  size_t i = blockIdx.x * 256ull + threadIdx.x;
  if (i >= (size_t)N_ * cpr) return;
  int row = (int)(i / cpr), c0 = (int)(i % cpr) * 4;
  float4 v = *(const float4*)&x[(size_t)row * K + c0];
  ushort4 h;
  h.x = __half_as_ushort(__float2half(v.x));
  h.y = __half_as_ushort(__float2half(v.y));
  h.z = __half_as_ushort(__float2half(v.z));
  h.w = __half_as_ushort(__float2half(v.w));
  *(ushort4*)&xh[(size_t)row * 128 + c0] = h;
  if (c0 == K - 4) {
    ushort4 z4 = {0, 0, 0, 0};
    uint4 z16 = {0, 0, 0, 0};
    *(ushort4*)&xh[(size_t)row * 128 + K] = z4;
    *(uint4*)&xh[(size_t)row * 128 + K + 4] = z16;
    *(uint4*)&xh[(size_t)row * 128 + K + 12] = z16;
    *(uint4*)&xh[(size_t)row * 128 + K + 20] = z16;
  }
}

// W (fp32 [Kreal][64]) -> wt (fp16 [64][KP], zero-padded transpose)
__global__ void k_wt(const float* __restrict__ W, unsigned short* __restrict__ wt,
                     int Kreal, int KP) {
  int idx = blockIdx.x * 256 + threadIdx.x;
  if (idx >= 64 * KP) return;
  int c = idx / KP, k = idx % KP;
  float v = (k < Kreal) ? W[k * DH + c] : 0.f;
  wt[idx] = __half_as_ushort(__float2half(v));
}

// Pass 1: bin edges by dst bucket. payload: hi=(dst&511)<<17|src, lo=fp32 ew.
__global__ __launch_bounds__(256) void k_bin0(
    const int* __restrict__ src, const int* __restrict__ dst,
    const float* __restrict__ ew, unsigned* __restrict__ gcur0,
    unsigned long long* __restrict__ bstage, int E_) {
  __shared__ unsigned cntL[NBUK], offL[NBUK], runL[NBUK];
  const int t = threadIdx.x;
  const int base = blockIdx.x * (256 * BINJ);
  cntL[t] = 0;
  runL[t] = 0;
  __syncthreads();
  unsigned hi[BINJ], lo[BINJ];
  int bb[BINJ];
#pragma unroll
  for (int j = 0; j < BINJ; ++j) {
    int e = base + j * 256 + t;
    bb[j] = -1;
    if (e < E_) {
      int q = dst[e];
      hi[j] = ((unsigned)(q & (BROWS - 1)) << 17) | (unsigned)src[e];
      lo[j] = __float_as_uint(ew[e]);
      bb[j] = q >> 9;
      atomicAdd(&cntL[bb[j]], 1u);
    }
  }
  __syncthreads();
  offL[t] = cntL[t] ? atomicAdd(&gcur0[t], cntL[t]) : 0u;
  __syncthreads();
#pragma unroll
  for (int j = 0; j < BINJ; ++j) {
    if (bb[j] >= 0) {
      unsigned p = offL[bb[j]] + atomicAdd(&runL[bb[j]], 1u);
      bstage[p] = ((unsigned long long)hi[j] << 32) | lo[j];
    }
  }
}

// Per-bucket histogram from staged runs (deterministic fixed-point sum).
__global__ __launch_bounds__(256) void k_bcnt(
    const unsigned long long* __restrict__ bstage, const unsigned* __restrict__ gcur0,
    int* __restrict__ cnt, float* __restrict__ dinv, float* __restrict__ sc, int N_) {
  __shared__ unsigned cntL[BROWS], degL[BROWS];
  const int b = blockIdx.x, t = threadIdx.x;
  for (int i = t; i < BROWS; i += 256) {
    cntL[i] = 0;
    degL[i] = 0;
  }
  __syncthreads();
  const unsigned beg = (unsigned)(b * CAP), end = gcur0[b];
  for (unsigned p = beg + t; p < end; p += 256) {
    unsigned long long v = bstage[p];
    unsigned r = (unsigned)(v >> 49);
    float w = __uint_as_float((unsigned)v);
    atomicAdd(&cntL[r], 1u);
    atomicAdd(&degL[r], (unsigned)(w * 16777216.0f));
  }
  __syncthreads();
  for (int i = t; i < BROWS; i += 256) {
    int r = b * BROWS + i;
    if (r < N_) {
      float deg = 1.0f + (float)degL[i] * (1.0f / 16777216.0f);
      cnt[r] = (int)cntL[i];
      dinv[r] = rsqrtf(deg);
      sc[r] = 1.0f / deg;
    }
  }
}

// ---- exclusive scan over n1 = N+1 values (raw cnt, pad-free) ----
__global__ __launch_bounds__(256) void k_scan1(const int* __restrict__ cnt,
                                               int* __restrict__ out,
                                               int* __restrict__ bsums,
                                               int N_, int n1) {
  __shared__ int sm[256];
  const int t = threadIdx.x;
  const int base = blockIdx.x * 1024 + t * 4;
  int v[4], lsum = 0;
#pragma unroll
  for (int j = 0; j < 4; ++j) {
    int i = base + j;
    v[j] = (i < N_) ? cnt[i] : 0;
    lsum += v[j];
  }
  sm[t] = lsum;
  __syncthreads();
  for (int o = 1; o < 256; o <<= 1) {
    int x = (t >= o) ? sm[t - o] : 0;
    __syncthreads();
    if (t >= o) sm[t] += x;
    __syncthreads();
  }
  int run = sm[t] - lsum;
#pragma unroll
  for (int j = 0; j < 4; ++j) {
    int i = base + j;
    if (i < n1) out[i] = run;
    run += v[j];
  }
  if (t == 255) bsums[blockIdx.x] = sm[255];
}

__global__ __launch_bounds__(256) void k_scan2(int* __restrict__ bsums, int nb) {
  __shared__ int sm[256];
  int t = threadIdx.x;
  int v = (t < nb) ? bsums[t] : 0;
  sm[t] = v;
  __syncthreads();
  for (int o = 1; o < 256; o <<= 1) {
    int x = (t >= o) ? sm[t - o] : 0;
    __syncthreads();
    if (t >= o) sm[t] += x;
    __syncthreads();
  }
  if (t < nb) bsums[t] = sm[t] - v;
}

__global__ void k_scan3(int* __restrict__ out, const int* __restrict__ bsums, int n1) {
  int i = blockIdx.x * blockDim.x + threadIdx.x;
  if (i < n1) out[i] += bsums[i >> 10];
}

// Pass 2: one block per bucket; norm + CSR placement via LDS cursors.
__global__ __launch_bounds__(256) void k_fin(
    const unsigned long long* __restrict__ bstage, const int* __restrict__ rowstart,
    const unsigned* __restrict__ gcur0, const float* __restrict__ dinv,
    unsigned* __restrict__ elist, int N_) {
  __shared__ unsigned lcur[BROWS];
  __shared__ int rsL[BROWS];
  __shared__ float dvL[BROWS];
  const int b = blockIdx.x, t = threadIdx.x;
  const int r0 = b * BROWS;
  for (int i = t; i < BROWS; i += 256) {
    lcur[i] = 0;
    int r = r0 + i;
    dvL[i] = (r < N_) ? dinv[r] : 0.f;
    rsL[i] = (r < N_) ? rowstart[r] : 0;
  }
  __syncthreads();
  const unsigned beg = (unsigned)(b * CAP), end = gcur0[b];
  for (unsigned p = beg + t; p < end; p += 256) {
    unsigned long long v = bstage[p];
    unsigned hi = (unsigned)(v >> 32);
    unsigned r = hi >> 17;
    unsigned s = hi & 0x1FFFFu;
    float w = __uint_as_float((unsigned)v);
    float nm = w * dinv[s] * dvL[r];
    unsigned h15 = (unsigned)__half_as_ushort(__float2half(nm));
    unsigned slot = (unsigned)rsL[r] + atomicAdd(&lcur[r], 1u);
    elist[slot] = (h15 << 17) | s;
  }
}

// graph boundary detection on sorted batch: gstart[g] for g in [0,G]
__global__ void k_gbound(const int* __restrict__ batch, int* __restrict__ gstart,
                         int N_, int G_) {
  int i = blockIdx.x * blockDim.x + threadIdx.x;
  if (i >= N_) return;
  int b = batch[i];
  if (i == 0) {
    for (int g = 0; g <= b; ++g) gstart[g] = 0;
  }
  int nb = (i + 1 < N_) ? batch[i + 1] : G_;
  for (int g = b + 1; g <= nb; ++g) gstart[g] = i + 1;
}

// MFMA GEMM: 128x64/block, 4 waves x (32x64). All-fp16 operands, 16B vector
// staging. A stride = KP (xh padded 128 / aggh 64). Writes fp16 H [N][64].
template <int KP, int FUSE>
__global__ __launch_bounds__(256) void k_gemm_mfma(
    const unsigned short* __restrict__ Aa, const unsigned short* __restrict__ wt,
    const float* __restrict__ bias, const float* __restrict__ stats,
    const float* __restrict__ gam, const float* __restrict__ bet,
    unsigned short* __restrict__ Hu, int n, float invN) {
  __shared__ unsigned short Ah[128 * KP];
  __shared__ unsigned short Bt[64 * KP];
  __shared__ float saL[DH], sbL[DH];
  const int tid = threadIdx.x;
  const int r0 = blockIdx.x * 128;
  if (FUSE) {
    if (tid < DH) {
      float mean = stats[tid] * invN;
      float var = stats[DH + tid] * invN - mean * mean;
      float a = rsqrtf(var + EPSV) * gam[tid];
      saL[tid] = a;
      sbL[tid] = bet[tid] - mean * a;
    }
    __syncthreads();
  }
  constexpr int KC = KP / 8;
  for (int ci = tid; ci < 128 * KC; ci += 256) {
    int row = ci / KC, kc = ci % KC, k0 = kc * 8;
    int gr = r0 + row;
    uint4 av = {0, 0, 0, 0};
    if (gr < n) av = *(const uint4*)&Aa[(size_t)gr * KP + k0];
    if (FUSE) {
      const unsigned short* ap = (const unsigned short*)&av;
      unsigned short ov[8];
#pragma unroll
      for (int j = 0; j < 8; ++j) {
        int k = k0 + j;
        float a = __half2float(__ushort_as_half(ap[j]));
        ov[j] = __half_as_ushort(__float2half(fmaxf(a * saL[k] + sbL[k], 0.f)));
      }
      av = *(uint4*)ov;
    }
    *(uint4*)&Ah[row * KP + (k0 ^ ((row & 7) * 8))] = av;
  }
  for (int ci = tid; ci < 64 * KC; ci += 256) {
    int c = ci / KC, kc = ci % KC, k0 = kc * 8;
    uint4 wv = *(const uint4*)&wt[c * KP + k0];
    *(uint4*)&Bt[c * KP + (k0 ^ ((c & 7) * 8))] = wv;
  }
  __syncthreads();
  const int w = tid >> 6, l = tid & 63;
  const int lr = l & 15, lg = l >> 4;
  f32x4 acc[2][4];
#pragma unroll
  for (int a1 = 0; a1 < 2; ++a1)
#pragma unroll
    for (int a2 = 0; a2 < 4; ++a2) acc[a1][a2] = (f32x4){0.f, 0.f, 0.f, 0.f};
#pragma unroll
  for (int ks = 0; ks < KP / 32; ++ks) {
    const int k0 = ks * 32 + lg * 8;
    half8 av[2], bv[4];
#pragma unroll
    for (int rf = 0; rf < 2; ++rf) {
      int row = w * 32 + rf * 16 + lr;
      av[rf] = *(const half8*)&Ah[row * KP + (k0 ^ ((row & 7) * 8))];
    }
#pragma unroll
    for (int cf = 0; cf < 4; ++cf) {
      int col = cf * 16 + lr;
      bv[cf] = *(const half8*)&Bt[col * KP + (k0 ^ ((col & 7) * 8))];
    }
#pragma unroll
    for (int rf = 0; rf < 2; ++rf)
#pragma unroll
      for (int cf = 0; cf < 4; ++cf)
        acc[rf][cf] =
            __builtin_amdgcn_mfma_f32_16x16x32_f16(av[rf], bv[cf], acc[rf][cf], 0, 0, 0);
  }
#pragma unroll
  for (int rf = 0; rf < 2; ++rf) {
#pragma unroll
    for (int cf = 0; cf < 4; ++cf) {
      int col = cf * 16 + lr;
      float bcol = bias[col];
#pragma unroll
      for (int i = 0; i < 4; ++i) {
        int row = r0 + w * 32 + rf * 16 + lg * 4 + i;
        if (row < n)
          Hu[(size_t)row * DH + col] = __half_as_ushort(__float2half(acc[rf][cf][i] + bcol));
      }
    }
  }
}

// Pull aggregation: one wave per dst row, lane d = feature d; pad-free
// (register roundup: lanes >= rem stage eL=0 -> norm 0 no-op FMAs).
__global__ __launch_bounds__(256) void k_gather(
    const unsigned* __restrict__ elist, const int* __restrict__ rowstart,
    const unsigned short* __restrict__ Hu, const float* __restrict__ sc,
    unsigned short* __restrict__ AGGu, float* __restrict__ statp, int n) {
  const int wid = threadIdx.x >> 6;
  const int d = threadIdx.x & 63;
  const int gw = blockIdx.x * 4 + wid;
  const int nw = gridDim.x * 4;
  float s = 0.f, ss = 0.f;
  for (int row = gw; row < n; row += nw) {
    const int rs = rowstart[row], re = rowstart[row + 1];
    float acc = __half2float(__ushort_as_half(Hu[(size_t)row * DH + d])) * sc[row];
    for (int base = rs; base < re; base += 64) {
      const int rem = re - base;
      unsigned eL = 0u;
      if (d < rem) eL = __builtin_nontemporal_load(&elist[base + d]);
      const int m = rem < 64 ? ((rem + 7) & ~7) : 64;
      for (int j = 0; j < m; j += 8) {
        unsigned e[8];
        float v[8];
#pragma unroll
        for (int jj = 0; jj < 8; ++jj) e[jj] = __shfl(eL, j + jj, 64);
#pragma unroll
        for (int jj = 0; jj < 8; ++jj)
          v[jj] = __half2float(__ushort_as_half(Hu[(size_t)(e[jj] & 0x1FFFFu) * DH + d]));
#pragma unroll
        for (int jj = 0; jj < 8; ++jj) {
          float nm = __half2float(__ushort_as_half((unsigned short)(e[jj] >> 17)));
          acc = fmaf(nm, v[jj], acc);
        }
      }
    }
    __builtin_nontemporal_store(__half_as_ushort(__float2half(acc)),
                                &AGGu[(size_t)row * DH + d]);
    s += acc;
    ss += acc * acc;
  }
  __shared__ float sm[4][DH], sm2[4][DH];
  sm[wid][d] = s;
  sm2[wid][d] = ss;
  __syncthreads();
  if (threadIdx.x < DH) {
    float a = sm[0][d] + sm[1][d] + sm[2][d] + sm[3][d];
    float b = sm2[0][d] + sm2[1][d] + sm2[2][d] + sm2[3][d];
    __builtin_nontemporal_store(a, &statp[(size_t)blockIdx.x * 128 + d]);
    __builtin_nontemporal_store(b, &statp[(size_t)blockIdx.x * 128 + DH + d]);
  }
}

// reduce per-block stat partials: one block per stat entry (128 blocks)
__global__ __launch_bounds__(256) void k_redstats(const float* __restrict__ statp,
                                                  float* __restrict__ stats, int nblk) {
  const int t = blockIdx.x;
  float s = 0.f;
  for (int b = threadIdx.x; b < nblk; b += 256) s += statp[(size_t)b * 128 + t];
#pragma unroll
  for (int o = 32; o > 0; o >>= 1) s += __shfl_down(s, o, 64);
  __shared__ float sm[4];
  if ((threadIdx.x & 63) == 0) sm[threadIdx.x >> 6] = s;
  __syncthreads();
  if (threadIdx.x == 0) stats[t] = sm[0] + sm[1] + sm[2] + sm[3];
}

// fused BN+ReLU+mean-pool+head: one block per graph.
__global__ __launch_bounds__(256) void k_poolhead(
    const unsigned short* __restrict__ AGGu, const float* __restrict__ stats,
    const float* __restrict__ gam, const float* __restrict__ bet,
    const float* __restrict__ ow, const int* __restrict__ gstart,
    const float* __restrict__ ob, float* __restrict__ out, float invN) {
  const int g = blockIdx.x;
  const int gs = gstart[g], ge = gstart[g + 1];
  const int wid = threadIdx.x >> 6;
  const int d = threadIdx.x & 63;
  float mean = stats[d] * invN;
  float var = stats[DH + d] * invN - mean * mean;
  float sa = rsqrtf(var + EPSV) * gam[d];
  float sb = bet[d] - mean * sa;
  const float w = ow[d];
  float acc = 0.f;
  for (int row = gs + wid; row < ge; row += 4) {
    float v = __half2float(__ushort_as_half(AGGu[(size_t)row * DH + d]));
    acc += fmaxf(v * sa + sb, 0.f) * w;
  }
#pragma unroll
  for (int off = 32; off > 0; off >>= 1) acc += __shfl_down(acc, off, 64);
  __shared__ float sm[4];
  if (d == 0) sm[wid] = acc;
  __syncthreads();
  if (threadIdx.x == 0) {
    float s = sm[0] + sm[1] + sm[2] + sm[3];
    float cnt = (float)(ge - gs);
    out[g] = s / fmaxf(cnt, 1.0f) + ob[0];
  }
}

extern "C" void kernel_launch(void* const* d_in, const int* in_sizes, int n_in,
                              void* d_out, int out_size, void* d_ws, size_t ws_size,
                              hipStream_t stream) {
  const float* x    = (const float*)d_in[0];
  const int*   ei   = (const int*)d_in[1];
  const float* ew   = (const float*)d_in[2];
  const int*   batch= (const int*)d_in[3];
  const float* w0   = (const float*)d_in[4];
  const float* b0   = (const float*)d_in[5];
  const float* g0   = (const float*)d_in[6];
  const float* be0  = (const float*)d_in[7];
  const float* w1   = (const float*)d_in[8];
  const float* b1   = (const float*)d_in[9];
  const float* g1   = (const float*)d_in[10];
  const float* be1  = (const float*)d_in[11];
  const float* w2   = (const float*)d_in[12];
  const float* b2   = (const float*)d_in[13];
  const float* g2   = (const float*)d_in[14];
  const float* be2  = (const float*)d_in[15];
  const float* ow   = (const float*)d_in[16];
  const float* ob   = (const float*)d_in[17];

  const int N_  = in_sizes[3];
  const int E_  = in_sizes[2];
  const int DIN_= in_sizes[0] / N_;
  const int G_  = out_size;
  const int* srcIdx = ei;
  const int* dstIdx = ei + E_;
  const int n1 = N_ + 1;

  float* ws = (float*)d_ws;
  size_t off = 0;
  unsigned long long* bstage = (unsigned long long*)(ws + off);
  off += (size_t)2 * NBUK * CAP;
  unsigned* elist = (unsigned*)(ws + off); off += E_;
  float* dinv     = ws + off; off += N_;
  float* sc       = ws + off; off += N_;
  int*   cnt      = (int*)(ws + off); off += N_;
  int*   rowstart = (int*)(ws + off); off += n1 + 1;
  int*   bsums    = (int*)(ws + off); off += 256;
  unsigned* gcur0 = (unsigned*)(ws + off); off += NBUK;
  int*   gstart   = (int*)(ws + off); off += G_ + 1;
  unsigned short* hbuf = (unsigned short*)(ws + off); off += (size_t)N_ * 32;
  unsigned short* aggb = (unsigned short*)(ws + off); off += (size_t)N_ * 32;
  unsigned short* xh = (unsigned short*)(ws + off); off += (size_t)N_ * 64;
  unsigned short* wt0 = (unsigned short*)(ws + off); off += 64 * 128 / 2;
  unsigned short* wt1 = (unsigned short*)(ws + off); off += 64 * 64 / 2;
  unsigned short* wt2 = (unsigned short*)(ws + off); off += 64 * 64 / 2;
  float* stats    = ws + off; off += 2 * DH;
  float* statp    = ws + off; off += (size_t)GBLK * 128;
  (void)ws_size; (void)n_in;

  // --- operand pre-conversion ---
  k_xhalf<<<(int)(((size_t)N_ * (DIN_ / 4) + 255) / 256), 256, 0, stream>>>(x, xh, N_, DIN_);
  k_wt<<<(64 * 128 + 255) / 256, 256, 0, stream>>>(w0, wt0, DIN_, 128);
  k_wt<<<(64 * 64 + 255) / 256, 256, 0, stream>>>(w1, wt1, DH, 64);
  k_wt<<<(64 * 64 + 255) / 256, 256, 0, stream>>>(w2, wt2, DH, 64);

  // --- binned CSR build (pad-free) ---
  k_gcur0<<<1, NBUK, 0, stream>>>(gcur0);
  k_bin0<<<(E_ + 256 * BINJ - 1) / (256 * BINJ), 256, 0, stream>>>(
      srcIdx, dstIdx, ew, gcur0, bstage, E_);
  k_bcnt<<<NBUK, 256, 0, stream>>>(bstage, gcur0, cnt, dinv, sc, N_);

  const int nb = (n1 + 1023) / 1024;
  k_scan1<<<nb, 256, 0, stream>>>(cnt, rowstart, bsums, N_, n1);
  k_scan2<<<1, 256, 0, stream>>>(bsums, nb);
  k_scan3<<<(n1 + 255) / 256, 256, 0, stream>>>(rowstart, bsums, n1);

  k_fin<<<NBUK, 256, 0, stream>>>(bstage, rowstart, gcur0, dinv, elist, N_);

  // --- graph boundaries for pooling ---
  k_gbound<<<(N_ + 255) / 256, 256, 0, stream>>>(batch, gstart, N_, G_);

  const float* Bl[3]  = {b0, b1, b2};
  const float* Gl[3]  = {g0, g1, g2};
  const float* BeL[3] = {be0, be1, be2};
  const unsigned short* Wt[3] = {wt0, wt1, wt2};

  const float invN = 1.0f / (float)N_;
  const int gblk = (N_ + 127) / 128;

  for (int l = 0; l < 3; ++l) {
    if (l == 0) {
      k_gemm_mfma<128, 0><<<gblk, 256, 0, stream>>>(
          xh, Wt[0], Bl[0], stats, nullptr, nullptr, hbuf, N_, invN);
    } else {
      k_gemm_mfma<64, 1><<<gblk, 256, 0, stream>>>(
          aggb, Wt[l], Bl[l], stats, Gl[l - 1], BeL[l - 1], hbuf, N_, invN);
    }
    k_gather<<<GBLK, 256, 0, stream>>>(elist, rowstart, hbuf, sc, aggb, statp, N_);
    k_redstats<<<128, 256, 0, stream>>>(statp, stats, GBLK);
  }

  // --- fused BN2+ReLU+pooling+head ---
  k_poolhead<<<G_, 256, 0, stream>>>(aggb, stats, g2, be2, ow, gstart, ob,
                                     (float*)d_out, invN);
}

// Round 16
// 326.665 us; speedup vs baseline: 1.2059x; 1.0311x over previous
//
#include <hip/hip_runtime.h>
#include <hip/hip_fp16.h>
#include <cstdint>

#define DH 64
#define EPSV 1e-5f
#define GBLK 2048
#define NBUK 256
#define BROWS 512
#define BINJ 8
#define CAP 12288

typedef _Float16 half8 __attribute__((ext_vector_type(8)));
typedef float f32x4 __attribute__((ext_vector_type(4)));

// Combined setup: graph boundaries + bucket cursors + 3x W transpose->fp16
__global__ __launch_bounds__(256) void k_setup(
    const int* __restrict__ batch, int* __restrict__ gstart,
    unsigned* __restrict__ gcur0,
    const float* __restrict__ w0, const float* __restrict__ w1,
    const float* __restrict__ w2, unsigned short* __restrict__ wt0,
    unsigned short* __restrict__ wt1, unsigned short* __restrict__ wt2,
    int N_, int G_, int DIN_, int nbN) {
  const int b = blockIdx.x, t = threadIdx.x;
  if (b < nbN) {
    int i = b * 256 + t;
    if (i >= N_) return;
    int bb = batch[i];
    if (i == 0) {
      for (int g = 0; g <= bb; ++g) gstart[g] = 0;
    }
    int nb2 = (i + 1 < N_) ? batch[i + 1] : G_;
    for (int g = bb + 1; g <= nb2; ++g) gstart[g] = i + 1;
  } else if (b == nbN) {
    if (t < NBUK) gcur0[t] = (unsigned)(t * CAP);
  } else {
    int idx = (b - nbN - 1) * 256 + t;
    if (idx < 64 * 128) {
      int c = idx / 128, k = idx % 128;
      wt0[idx] = __half_as_ushort(__float2half(k < DIN_ ? w0[k * DH + c] : 0.f));
    } else if (idx < 64 * 128 + 64 * 64) {
      int l2 = idx - 64 * 128;
      int c = l2 / 64, k = l2 % 64;
      wt1[l2] = __half_as_ushort(__float2half(w1[k * DH + c]));
    } else if (idx < 64 * 128 + 2 * 64 * 64) {
      int l2 = idx - 64 * 128 - 64 * 64;
      int c = l2 / 64, k = l2 % 64;
      wt2[l2] = __half_as_ushort(__float2half(w2[k * DH + c]));
    }
  }
}

// Pass 1: bin edges by dst bucket. payload: hi=(dst&511)<<17|src, lo=fp32 ew.
__global__ __launch_bounds__(256) void k_bin0(
    const int* __restrict__ src, const int* __restrict__ dst,
    const float* __restrict__ ew, unsigned* __restrict__ gcur0,
    unsigned long long* __restrict__ bstage, int E_) {
  __shared__ unsigned cntL[NBUK], offL[NBUK], runL[NBUK];
  const int t = threadIdx.x;
  const int base = blockIdx.x * (256 * BINJ);
  cntL[t] = 0;
  runL[t] = 0;
  __syncthreads();
  unsigned hi[BINJ], lo[BINJ];
  int bb[BINJ];
#pragma unroll
  for (int j = 0; j < BINJ; ++j) {
    int e = base + j * 256 + t;
    bb[j] = -1;
    if (e < E_) {
      int q = dst[e];
      hi[j] = ((unsigned)(q & (BROWS - 1)) << 17) | (unsigned)src[e];
      lo[j] = __float_as_uint(ew[e]);
      bb[j] = q >> 9;
      atomicAdd(&cntL[bb[j]], 1u);
    }
  }
  __syncthreads();
  offL[t] = cntL[t] ? atomicAdd(&gcur0[t], cntL[t]) : 0u;
  __syncthreads();
#pragma unroll
  for (int j = 0; j < BINJ; ++j) {
    if (bb[j] >= 0) {
      unsigned p = offL[bb[j]] + atomicAdd(&runL[bb[j]], 1u);
      bstage[p] = ((unsigned long long)hi[j] << 32) | lo[j];
    }
  }
}

// Per-bucket histogram from staged runs (deterministic fixed-point sum).
__global__ __launch_bounds__(256) void k_bcnt(
    const unsigned long long* __restrict__ bstage, const unsigned* __restrict__ gcur0,
    int* __restrict__ cnt, float* __restrict__ dinv, float* __restrict__ sc, int N_) {
  __shared__ unsigned cntL[BROWS], degL[BROWS];
  const int b = blockIdx.x, t = threadIdx.x;
  for (int i = t; i < BROWS; i += 256) {
    cntL[i] = 0;
    degL[i] = 0;
  }
  __syncthreads();
  const unsigned beg = (unsigned)(b * CAP), end = gcur0[b];
  for (unsigned p = beg + t; p < end; p += 256) {
    unsigned long long v = bstage[p];
    unsigned r = (unsigned)(v >> 49);
    float w = __uint_as_float((unsigned)v);
    atomicAdd(&cntL[r], 1u);
    atomicAdd(&degL[r], (unsigned)(w * 16777216.0f));
  }
  __syncthreads();
  for (int i = t; i < BROWS; i += 256) {
    int r = b * BROWS + i;
    if (r < N_) {
      float deg = 1.0f + (float)degL[i] * (1.0f / 16777216.0f);
      cnt[r] = (int)cntL[i];
      dinv[r] = rsqrtf(deg);
      sc[r] = 1.0f / deg;
    }
  }
}

// ---- exclusive scan over n1 = N+1 values (raw cnt, pad-free) ----
__global__ __launch_bounds__(256) void k_scan1(const int* __restrict__ cnt,
                                               int* __restrict__ out,
                                               int* __restrict__ bsums,
                                               int N_, int n1) {
  __shared__ int sm[256];
  const int t = threadIdx.x;
  const int base = blockIdx.x * 1024 + t * 4;
  int v[4], lsum = 0;
#pragma unroll
  for (int j = 0; j < 4; ++j) {
    int i = base + j;
    v[j] = (i < N_) ? cnt[i] : 0;
    lsum += v[j];
  }
  sm[t] = lsum;
  __syncthreads();
  for (int o = 1; o < 256; o <<= 1) {
    int x = (t >= o) ? sm[t - o] : 0;
    __syncthreads();
    if (t >= o) sm[t] += x;
    __syncthreads();
  }
  int run = sm[t] - lsum;
#pragma unroll
  for (int j = 0; j < 4; ++j) {
    int i = base + j;
    if (i < n1) out[i] = run;
    run += v[j];
  }
  if (t == 255) bsums[blockIdx.x] = sm[255];
}

__global__ __launch_bounds__(256) void k_scan2(int* __restrict__ bsums, int nb) {
  __shared__ int sm[256];
  int t = threadIdx.x;
  int v = (t < nb) ? bsums[t] : 0;
  sm[t] = v;
  __syncthreads();
  for (int o = 1; o < 256; o <<= 1) {
    int x = (t >= o) ? sm[t - o] : 0;
    __syncthreads();
    if (t >= o) sm[t] += x;
    __syncthreads();
  }
  if (t < nb) bsums[t] = sm[t] - v;
}

__global__ void k_scan3(int* __restrict__ out, const int* __restrict__ bsums, int n1) {
  int i = blockIdx.x * blockDim.x + threadIdx.x;
  if (i < n1) out[i] += bsums[i >> 10];
}

// Pass 2: one block per bucket; norm + CSR placement via LDS cursors.
__global__ __launch_bounds__(256) void k_fin(
    const unsigned long long* __restrict__ bstage, const int* __restrict__ rowstart,
    const unsigned* __restrict__ gcur0, const float* __restrict__ dinv,
    unsigned* __restrict__ elist, int N_) {
  __shared__ unsigned lcur[BROWS];
  __shared__ int rsL[BROWS];
  __shared__ float dvL[BROWS];
  const int b = blockIdx.x, t = threadIdx.x;
  const int r0 = b * BROWS;
  for (int i = t; i < BROWS; i += 256) {
    lcur[i] = 0;
    int r = r0 + i;
    dvL[i] = (r < N_) ? dinv[r] : 0.f;
    rsL[i] = (r < N_) ? rowstart[r] : 0;
  }
  __syncthreads();
  const unsigned beg = (unsigned)(b * CAP), end = gcur0[b];
  for (unsigned p = beg + t; p < end; p += 256) {
    unsigned long long v = bstage[p];
    unsigned hi = (unsigned)(v >> 32);
    unsigned r = hi >> 17;
    unsigned s = hi & 0x1FFFFu;
    float w = __uint_as_float((unsigned)v);
    float nm = w * dinv[s] * dvL[r];
    unsigned h15 = (unsigned)__half_as_ushort(__float2half(nm));
    unsigned slot = (unsigned)rsL[r] + atomicAdd(&lcur[r], 1u);
    elist[slot] = (h15 << 17) | s;
  }
}

// MFMA GEMM: 128x64/block, 4 waves x (32x64). 16B vector staging.
// FUSE=0: A = fp32 x [n][Kreal], staged->fp16 (KP=128 zero-padded).
// FUSE=1: A = fp16 agg [n][64] with BN(prev)+ReLU fused. Writes fp16 H [N][64].
template <int KP, int FUSE>
__global__ __launch_bounds__(256) void k_gemm_mfma(
    const void* __restrict__ Ap, const unsigned short* __restrict__ wt,
    const float* __restrict__ bias, const float* __restrict__ stats,
    const float* __restrict__ gam, const float* __restrict__ bet,
    unsigned short* __restrict__ Hu, int n, int Kreal, float invN) {
  __shared__ unsigned short Ah[128 * KP];
  __shared__ unsigned short Bt[64 * KP];
  __shared__ float saL[DH], sbL[DH];
  const int tid = threadIdx.x;
  const int r0 = blockIdx.x * 128;
  if (FUSE) {
    if (tid < DH) {
      float mean = stats[tid] * invN;
      float var = stats[DH + tid] * invN - mean * mean;
      float a = rsqrtf(var + EPSV) * gam[tid];
      saL[tid] = a;
      sbL[tid] = bet[tid] - mean * a;
    }
    __syncthreads();
  }
  constexpr int KC = KP / 8;
  for (int ci = tid; ci < 128 * KC; ci += 256) {
    int row = ci / KC, kc = ci % KC, k0 = kc * 8;
    int gr = r0 + row;
    uint4 av = {0, 0, 0, 0};
    if (FUSE) {
      const unsigned short* Aa = (const unsigned short*)Ap;
      if (gr < n) av = *(const uint4*)&Aa[(size_t)gr * KP + k0];
      const unsigned short* ap = (const unsigned short*)&av;
      unsigned short ov[8];
#pragma unroll
      for (int j = 0; j < 8; ++j) {
        int k = k0 + j;
        float a = __half2float(__ushort_as_half(ap[j]));
        ov[j] = __half_as_ushort(__float2half(fmaxf(a * saL[k] + sbL[k], 0.f)));
      }
      av = *(uint4*)ov;
    } else {
      const float* Ax = (const float*)Ap;
      unsigned short ov[8] = {0, 0, 0, 0, 0, 0, 0, 0};
      if (gr < n) {
        if (k0 + 8 <= Kreal) {
          float4 a = *(const float4*)&Ax[(size_t)gr * Kreal + k0];
          float4 b = *(const float4*)&Ax[(size_t)gr * Kreal + k0 + 4];
          ov[0] = __half_as_ushort(__float2half(a.x));
          ov[1] = __half_as_ushort(__float2half(a.y));
          ov[2] = __half_as_ushort(__float2half(a.z));
          ov[3] = __half_as_ushort(__float2half(a.w));
          ov[4] = __half_as_ushort(__float2half(b.x));
          ov[5] = __half_as_ushort(__float2half(b.y));
          ov[6] = __half_as_ushort(__float2half(b.z));
          ov[7] = __half_as_ushort(__float2half(b.w));
        } else if (k0 < Kreal) {
#pragma unroll
          for (int j = 0; j < 8; ++j) {
            int k = k0 + j;
            if (k < Kreal)
              ov[j] = __half_as_ushort(__float2half(Ax[(size_t)gr * Kreal + k]));
          }
        }
      }
      av = *(uint4*)ov;
    }
    *(uint4*)&Ah[row * KP + (k0 ^ ((row & 7) * 8))] = av;
  }
  for (int ci = tid; ci < 64 * KC; ci += 256) {
    int c = ci / KC, kc = ci % KC, k0 = kc * 8;
    uint4 wv = *(const uint4*)&wt[c * KP + k0];
    *(uint4*)&Bt[c * KP + (k0 ^ ((c & 7) * 8))] = wv;
  }
  __syncthreads();
  const int w = tid >> 6, l = tid & 63;
  const int lr = l & 15, lg = l >> 4;
  f32x4 acc[2][4];
#pragma unroll
  for (int a1 = 0; a1 < 2; ++a1)
#pragma unroll
    for (int a2 = 0; a2 < 4; ++a2) acc[a1][a2] = (f32x4){0.f, 0.f, 0.f, 0.f};
#pragma unroll
  for (int ks = 0; ks < KP / 32; ++ks) {
    const int k0 = ks * 32 + lg * 8;
    half8 av[2], bv[4];
#pragma unroll
    for (int rf = 0; rf < 2; ++rf) {
      int row = w * 32 + rf * 16 + lr;
      av[rf] = *(const half8*)&Ah[row * KP + (k0 ^ ((row & 7) * 8))];
    }
#pragma unroll
    for (int cf = 0; cf < 4; ++cf) {
      int col = cf * 16 + lr;
      bv[cf] = *(const half8*)&Bt[col * KP + (k0 ^ ((col & 7) * 8))];
    }
#pragma unroll
    for (int rf = 0; rf < 2; ++rf)
#pragma unroll
      for (int cf = 0; cf < 4; ++cf)
        acc[rf][cf] =
            __builtin_amdgcn_mfma_f32_16x16x32_f16(av[rf], bv[cf], acc[rf][cf], 0, 0, 0);
  }
#pragma unroll
  for (int rf = 0; rf < 2; ++rf) {
#pragma unroll
    for (int cf = 0; cf < 4; ++cf) {
      int col = cf * 16 + lr;
      float bcol = bias[col];
#pragma unroll
      for (int i = 0; i < 4; ++i) {
        int row = r0 + w * 32 + rf * 16 + lg * 4 + i;
        if (row < n)
          Hu[(size_t)row * DH + col] = __half_as_ushort(__float2half(acc[rf][cf][i] + bcol));
      }
    }
  }
}

// Pull aggregation: one wave per dst row, lane d = feature d; pad-free.
__global__ __launch_bounds__(256) void k_gather(
    const unsigned* __restrict__ elist, const int* __restrict__ rowstart,
    const unsigned short* __restrict__ Hu, const float* __restrict__ sc,
    unsigned short* __restrict__ AGGu, float* __restrict__ statp, int n) {
  const int wid = threadIdx.x >> 6;
  const int d = threadIdx.x & 63;
  const int gw = blockIdx.x * 4 + wid;
  const int nw = gridDim.x * 4;
  float s = 0.f, ss = 0.f;
  for (int row = gw; row < n; row += nw) {
    const int rs = rowstart[row], re = rowstart[row + 1];
    float acc = __half2float(__ushort_as_half(Hu[(size_t)row * DH + d])) * sc[row];
    for (int base = rs; base < re; base += 64) {
      const int rem = re - base;
      unsigned eL = 0u;
      if (d < rem) eL = __builtin_nontemporal_load(&elist[base + d]);
      const int m = rem < 64 ? ((rem + 7) & ~7) : 64;
      for (int j = 0; j < m; j += 8) {
        unsigned e[8];
        float v[8];
#pragma unroll
        for (int jj = 0; jj < 8; ++jj) e[jj] = __shfl(eL, j + jj, 64);
#pragma unroll
        for (int jj = 0; jj < 8; ++jj)
          v[jj] = __half2float(__ushort_as_half(Hu[(size_t)(e[jj] & 0x1FFFFu) * DH + d]));
#pragma unroll
        for (int jj = 0; jj < 8; ++jj) {
          float nm = __half2float(__ushort_as_half((unsigned short)(e[jj] >> 17)));
          acc = fmaf(nm, v[jj], acc);
        }
      }
    }
    __builtin_nontemporal_store(__half_as_ushort(__float2half(acc)),
                                &AGGu[(size_t)row * DH + d]);
    s += acc;
    ss += acc * acc;
  }
  __shared__ float sm[4][DH], sm2[4][DH];
  sm[wid][d] = s;
  sm2[wid][d] = ss;
  __syncthreads();
  if (threadIdx.x < DH) {
    float a = sm[0][d] + sm[1][d] + sm[2][d] + sm[3][d];
    float b = sm2[0][d] + sm2[1][d] + sm2[2][d] + sm2[3][d];
    __builtin_nontemporal_store(a, &statp[(size_t)blockIdx.x * 128 + d]);
    __builtin_nontemporal_store(b, &statp[(size_t)blockIdx.x * 128 + DH + d]);
  }
}

// reduce per-block stat partials: one block per stat entry (128 blocks)
__global__ __launch_bounds__(256) void k_redstats(const float* __restrict__ statp,
                                                  float* __restrict__ stats, int nblk) {
  const int t = blockIdx.x;
  float s = 0.f;
  for (int b = threadIdx.x; b < nblk; b += 256) s += statp[(size_t)b * 128 + t];
#pragma unroll
  for (int o = 32; o > 0; o >>= 1) s += __shfl_down(s, o, 64);
  __shared__ float sm[4];
  if ((threadIdx.x & 63) == 0) sm[threadIdx.x >> 6] = s;
  __syncthreads();
  if (threadIdx.x == 0) stats[t] = sm[0] + sm[1] + sm[2] + sm[3];
}

// fused BN+ReLU+mean-pool+head: one block per graph.
__global__ __launch_bounds__(256) void k_poolhead(
    const unsigned short* __restrict__ AGGu, const float* __restrict__ stats,
    const float* __restrict__ gam, const float* __restrict__ bet,
    const float* __restrict__ ow, const int* __restrict__ gstart,
    const float* __restrict__ ob, float* __restrict__ out, float invN) {
  const int g = blockIdx.x;
  const int gs = gstart[g], ge = gstart[g + 1];
  const int wid = threadIdx.x >> 6;
  const int d = threadIdx.x & 63;
  float mean = stats[d] * invN;
  float var = stats[DH + d] * invN - mean * mean;
  float sa = rsqrtf(var + EPSV) * gam[d];
  float sb = bet[d] - mean * sa;
  const float w = ow[d];
  float acc = 0.f;
  for (int row = gs + wid; row < ge; row += 4) {
    float v = __half2float(__ushort_as_half(AGGu[(size_t)row * DH + d]));
    acc += fmaxf(v * sa + sb, 0.f) * w;
  }
#pragma unroll
  for (int off = 32; off > 0; off >>= 1) acc += __shfl_down(acc, off, 64);
  __shared__ float sm[4];
  if (d == 0) sm[wid] = acc;
  __syncthreads();
  if (threadIdx.x == 0) {
    float s = sm[0] + sm[1] + sm[2] + sm[3];
    float cnt = (float)(ge - gs);
    out[g] = s / fmaxf(cnt, 1.0f) + ob[0];
  }
}

extern "C" void kernel_launch(void* const* d_in, const int* in_sizes, int n_in,
                              void* d_out, int out_size, void* d_ws, size_t ws_size,
                              hipStream_t stream) {
  const float* x    = (const float*)d_in[0];
  const int*   ei   = (const int*)d_in[1];
  const float* ew   = (const float*)d_in[2];
  const int*   batch= (const int*)d_in[3];
  const float* w0   = (const float*)d_in[4];
  const float* b0   = (const float*)d_in[5];
  const float* g0   = (const float*)d_in[6];
  const float* be0  = (const float*)d_in[7];
  const float* w1   = (const float*)d_in[8];
  const float* b1   = (const float*)d_in[9];
  const float* g1   = (const float*)d_in[10];
  const float* be1  = (const float*)d_in[11];
  const float* w2   = (const float*)d_in[12];
  const float* b2   = (const float*)d_in[13];
  const float* g2   = (const float*)d_in[14];
  const float* be2  = (const float*)d_in[15];
  const float* ow   = (const float*)d_in[16];
  const float* ob   = (const float*)d_in[17];

  const int N_  = in_sizes[3];
  const int E_  = in_sizes[2];
  const int DIN_= in_sizes[0] / N_;
  const int G_  = out_size;
  const int* srcIdx = ei;
  const int* dstIdx = ei + E_;
  const int n1 = N_ + 1;

  float* ws = (float*)d_ws;
  size_t off = 0;
  unsigned long long* bstage = (unsigned long long*)(ws + off);
  off += (size_t)2 * NBUK * CAP;
  unsigned* elist = (unsigned*)(ws + off); off += E_;
  float* dinv     = ws + off; off += N_;
  float* sc       = ws + off; off += N_;
  int*   cnt      = (int*)(ws + off); off += N_;
  int*   rowstart = (int*)(ws + off); off += n1 + 1;
  int*   bsums    = (int*)(ws + off); off += 256;
  unsigned* gcur0 = (unsigned*)(ws + off); off += NBUK;
  int*   gstart   = (int*)(ws + off); off += G_ + 1;
  unsigned short* hbuf = (unsigned short*)(ws + off); off += (size_t)N_ * 32;
  unsigned short* aggb = (unsigned short*)(ws + off); off += (size_t)N_ * 32;
  unsigned short* wt0 = (unsigned short*)(ws + off); off += 64 * 128 / 2;
  unsigned short* wt1 = (unsigned short*)(ws + off); off += 64 * 64 / 2;
  unsigned short* wt2 = (unsigned short*)(ws + off); off += 64 * 64 / 2;
  float* stats    = ws + off; off += 2 * DH;
  float* statp    = ws + off; off += (size_t)GBLK * 128;
  (void)ws_size; (void)n_in;

  // --- combined setup (gbound + gcur0 + W transposes) ---
  const int nbN = (N_ + 255) / 256;
  const int wtBlocks = (64 * 128 + 2 * 64 * 64 + 255) / 256;
  k_setup<<<nbN + 1 + wtBlocks, 256, 0, stream>>>(
      batch, gstart, gcur0, w0, w1, w2, wt0, wt1, wt2, N_, G_, DIN_, nbN);

  // --- binned CSR build (pad-free) ---
  k_bin0<<<(E_ + 256 * BINJ - 1) / (256 * BINJ), 256, 0, stream>>>(
      srcIdx, dstIdx, ew, gcur0, bstage, E_);
  k_bcnt<<<NBUK, 256, 0, stream>>>(bstage, gcur0, cnt, dinv, sc, N_);

  const int nb = (n1 + 1023) / 1024;
  k_scan1<<<nb, 256, 0, stream>>>(cnt, rowstart, bsums, N_, n1);
  k_scan2<<<1, 256, 0, stream>>>(bsums, nb);
  k_scan3<<<(n1 + 255) / 256, 256, 0, stream>>>(rowstart, bsums, n1);

  k_fin<<<NBUK, 256, 0, stream>>>(bstage, rowstart, gcur0, dinv, elist, N_);

  const float* Bl[3]  = {b0, b1, b2};
  const float* Gl[3]  = {g0, g1, g2};
  const float* BeL[3] = {be0, be1, be2};
  const unsigned short* Wt[3] = {wt0, wt1, wt2};

  const float invN = 1.0f / (float)N_;
  const int gblk = (N_ + 127) / 128;

  for (int l = 0; l < 3; ++l) {
    if (l == 0) {
      k_gemm_mfma<128, 0><<<gblk, 256, 0, stream>>>(
          (const void*)x, Wt[0], Bl[0], stats, nullptr, nullptr, hbuf, N_, DIN_, invN);
    } else {
      k_gemm_mfma<64, 1><<<gblk, 256, 0, stream>>>(
          (const void*)aggb, Wt[l], Bl[l], stats, Gl[l - 1], BeL[l - 1], hbuf, N_, DH, invN);
    }
    k_gather<<<GBLK, 256, 0, stream>>>(elist, rowstart, hbuf, sc, aggb, statp, N_);
    k_redstats<<<128, 256, 0, stream>>>(statp, stats, GBLK);
  }

  // --- fused BN2+ReLU+pooling+head ---
  k_poolhead<<<G_, 256, 0, stream>>>(aggb, stats, g2, be2, ow, gstart, ob,
                                     (float*)d_out, invN);
}